// Round 3
// baseline (120.822 us; speedup 1.0000x reference)
//
#include <hip/hip_runtime.h>
#include <hip/hip_bf16.h>

// ---------------------------------------------------------------------------
// KroneNet fused kernel v11 for MI355X (gfx950)
// out[i][j] = softmax_j( s_a[i] * t_j[i] )
// History: v8 40.9us / v9 ~36.5us / v10 FAILED (red4 used row_half_mirror/
// row_mirror for the xor4/xor8 stages after the bit0/bit1 mux; mirrors are
// xor7/xor15 and require low-bit uniformity which the mux destroys ->
// sample r mixed with sample 3-r, absmax 3.1e-2).
// v11 = v10 with red4 fixed: last two stages use row_ror:4 / row_ror:8
// rotations (any rotation transversal sums the four 4-group partials and
// preserves c&3, so the a-index never mixes). Same inst count.
// Carried v10 features:
//   - W2 double-buffered in LDS (77KB, 2 blocks/CU = 154KB <= 160KB), ONE
//     __syncthreads total; SA is within-wave so no barriers after
//   - acc init via s=0 MFMA C-operand = replicated-b2 LDS tile (zero movs)
//   - layer-1 via v_pk_fma_f32 pairs (W1 stored {c0x,c1x,c0y,c1y}+{z0,z1})
//   - red4 multiplexed DPP butterfly (SEL4 cndmask chains deleted)
//   - softmax in log2 domain (SA pre-scaled by log2e), v_rcp divide,
//     spread store (cols 0-11 carry e0/e1/e2)
// ---------------------------------------------------------------------------

#define BTOT 262144
#define NBLK (BTOT / 512)   // 512 blocks x 512 samples (8 waves x 64)

typedef __attribute__((ext_vector_type(4))) float floatx4;
typedef __attribute__((ext_vector_type(2))) float floatx2;
typedef __attribute__((ext_vector_type(8))) short bf16x8;
typedef __attribute__((ext_vector_type(4))) int  intx4;

// LDS layout (bytes)
#define OFF_W2A  0          // 32768
#define OFF_W2B  32768      // 32768
#define OFF_PA   65536      // 64 * float4  {c0x,c1x,c0y,c1y}      = 1024
#define OFF_PB   66560      // 1024
#define OFF_ZA   67584      // 64 * float2  {b1[2e], b1[2e+1]}     = 512
#define OFF_ZB   68096      // 512
#define OFF_B2A  68608      // 128 * float4 (b2 replicated x4)     = 2048
#define OFF_B2B  70656      // 2048
#define OFF_W3A  72704      // 128 * float                         = 512
#define OFF_W3T  73216      // 128 * float4 (w3b transposed [n][j])= 2048
#define OFF_SA   75264      // 512 * float (s_a * log2e)           = 2048
#define LDS_TOTAL 77312

// pack two fp32 -> one dword of two bf16, single VALU op (RNE)
static __device__ __forceinline__ int pack2bf(float lo, float hi) {
    int r;
    asm("v_cvt_pk_bf16_f32 %0, %1, %2" : "=v"(r) : "v"(lo), "v"(hi));
    return r;
}

// DPP-fused butterfly add: v += lanes-permuted(v), 1 VALU inst per stage.
// 0xB1=quad_perm xor1, 0x4E=quad_perm xor2,
// 0x124=row_ror:4, 0x128=row_ror:8 (true rotations within the 16-lane row)
template <int CTRL>
static __device__ __forceinline__ float dppadd(float v) {
    int t = __builtin_amdgcn_update_dpp(0, __builtin_bit_cast(int, v),
                                        CTRL, 0xF, 0xF, true);
    return v + __builtin_bit_cast(float, t);
}

// Multiplexed 4-value reduce over 16 cols: 12 insts; lane c ends up with
// sum over all 16 cols of a_{c&3}  (so cols 0..3 hold a0..a3 directly).
// Stage 1: xor1-add each a_i, mux on bit0 (lanes c,c^2.. share bit0, valid).
// Stage 2: xor2-add, mux on bit1.  After this lane c holds the 4-group sum
// of a_{c&3} -- NOT uniform in low bits, so mirrors (xor7/xor15) are WRONG
// here (v10 bug).  Stages 3,4: row_ror:4 + row_ror:8 rotations -- a
// rotation transversal {c, c+4, c+8, c+12} sums all four group partials
// and (c+4k)&3 == c&3 keeps the a-index fixed.
static __device__ __forceinline__ float red4(float a0, float a1, float a2,
                                             float a3, int col) {
    float s0 = dppadd<0xB1>(a0), s1 = dppadd<0xB1>(a1);
    float s2 = dppadd<0xB1>(a2), s3 = dppadd<0xB1>(a3);
    float u0 = (col & 1) ? s1 : s0;
    float u1 = (col & 1) ? s3 : s2;
    float v0 = dppadd<0x4E>(u0), v1 = dppadd<0x4E>(u1);
    float w  = (col & 2) ? v1 : v0;
    w = dppadd<0x124>(w);   // += m[c+4]
    w = dppadd<0x128>(w);   // += m[c+8] + m[c+12]
    return w;
}

// Pack one path's W2 into one LDS buffer (512 threads, 8 iters).
// W2 mapping (verified v5-v9): k=4*k4: dest = (s*8+t)*1024 + l*16 + (k&7)*2,
// s=k>>5, l=((k&31)>>3)*16+(n&15), t=n>>4. Lane remap keeps write
// conflicts <=4-way.
static __device__ __forceinline__ void pack_w2(
        unsigned char* dst, int tid, const float* __restrict__ w2) {
    const float4* w2p = (const float4*)w2;
    #pragma unroll
    for (int i = 0; i < 8; ++i) {
        int n  = (tid & 15) | (i << 4);
        int k4 = tid >> 4;
        float4 f = w2p[n * 32 + k4];
        int k = k4 * 4;
        int s = k >> 5;
        int j0 = k & 7;               // 0 or 4
        int l = ((k & 31) >> 3) * 16 + (n & 15);
        int2 pkd;
        pkd.x = pack2bf(f.x, f.y);
        pkd.y = pack2bf(f.z, f.w);
        *(int2*)(dst + (s * 8 + (n >> 4)) * 1024 + l * 16 + j0 * 2) = pkd;
    }
}

// W1 pair-stage: entry e (0..63) covers k-pair (2e, 2e+1).
// P[e] = {w1[4e], w1[4e+2], w1[4e+1], w1[4e+3]}  (x-coef pair, y-coef pair)
// Z[e] = {b1[2e], b1[2e+1]}
static __device__ __forceinline__ void stage_w1(
        unsigned char* smem, int offP, int offZ, int e,
        const float* __restrict__ w1, const float* __restrict__ b1) {
    floatx4 g = ((const floatx4*)w1)[e];
    ((floatx4*)(smem + offP))[e] = (floatx4){g.x, g.z, g.y, g.w};
    ((floatx2*)(smem + offZ))[e] = (floatx2){b1[2 * e], b1[2 * e + 1]};
}

// One chunk's GEMM: acc = W2 . relu(W1.x+b1) + b2.
// b2 enters as the C operand of the s=0 MFMA (replicated-b2 LDS tile).
// acc layout: (t, mt, r) -> sample mt*16+quad*4+r, n = t*16+col.
#define GEMM_CHUNK(acc, XV, Pp, Zp, W2p, B2Rp)                                 \
    {                                                                          \
        floatx2 xx[2], xy[2];                                                  \
        _Pragma("unroll")                                                      \
        for (int mt = 0; mt < 2; ++mt) {                                       \
            xx[mt] = (floatx2){(XV)[mt].x, (XV)[mt].x};                        \
            xy[mt] = (floatx2){(XV)[mt].y, (XV)[mt].y};                        \
        }                                                                      \
        _Pragma("unroll")                                                      \
        for (int s = 0; s < 4; ++s) {                                          \
            intx4 af[2];                                                       \
            const int ebase = s * 16 + quad * 4;                               \
            _Pragma("unroll")                                                  \
            for (int j2 = 0; j2 < 4; ++j2) {                                   \
                floatx4 P = (Pp)[ebase + j2];                                  \
                floatx2 Z = (Zp)[ebase + j2];                                  \
                _Pragma("unroll")                                              \
                for (int mt = 0; mt < 2; ++mt) {                               \
                    floatx2 tt = __builtin_elementwise_fma(                    \
                        xy[mt], (floatx2){P.z, P.w}, Z);                       \
                    floatx2 h = __builtin_elementwise_fma(                     \
                        xx[mt], (floatx2){P.x, P.y}, tt);                      \
                    af[mt][j2] = pack2bf(fmaxf(h.x, 0.f), fmaxf(h.y, 0.f));    \
                }                                                              \
            }                                                                  \
            _Pragma("unroll")                                                  \
            for (int t = 0; t < 8; ++t) {                                      \
                bf16x8 bfr = (W2p)[(s * 8 + t) * 64 + lane];                   \
                if (s == 0) {                                                  \
                    floatx4 bias = (B2Rp)[t * 16 + col];                       \
                    _Pragma("unroll")                                          \
                    for (int mt = 0; mt < 2; ++mt)                             \
                        acc[t][mt] = __builtin_amdgcn_mfma_f32_16x16x32_bf16(  \
                            __builtin_bit_cast(bf16x8, af[mt]), bfr,           \
                            bias, 0, 0, 0);                                    \
                } else {                                                       \
                    _Pragma("unroll")                                          \
                    for (int mt = 0; mt < 2; ++mt)                             \
                        acc[t][mt] = __builtin_amdgcn_mfma_f32_16x16x32_bf16(  \
                            __builtin_bit_cast(bf16x8, af[mt]), bfr,           \
                            acc[t][mt], 0, 0, 0);                              \
                }                                                              \
            }                                                                  \
        }                                                                      \
    }

// ---------------------------------------------------------------------------
// 512 blocks x 512 threads (8 waves). Per block (512 samples):
//   stage EVERYTHING (both paths) -> one sync -> phase a (s_a->LDS) ->
//   phase b (t_j, softmax with LDS s_a, store) with no further barriers.
// ---------------------------------------------------------------------------
__global__ __launch_bounds__(512, 4)
void krone_fused(const float* __restrict__ x,
                 const float* __restrict__ w1a, const float* __restrict__ w1b,
                 const float* __restrict__ b1a, const float* __restrict__ b1b,
                 const float* __restrict__ w2a, const float* __restrict__ w2b,
                 const float* __restrict__ b2a, const float* __restrict__ b2b,
                 const float* __restrict__ w3a, const float* __restrict__ w3b,
                 const float* __restrict__ b3a, const float* __restrict__ b3b,
                 float* __restrict__ out) {
    __shared__ __align__(16) unsigned char smem[LDS_TOTAL];

    const int tid  = threadIdx.x;
    const int lane = tid & 63;
    const int wave = tid >> 6;
    const int quad = lane >> 4;
    const int col  = lane & 15;
    const int wbase = blockIdx.x * 512 + wave * 64;

    const bf16x8*  W2A = (const bf16x8*)(smem + OFF_W2A);
    const bf16x8*  W2B = (const bf16x8*)(smem + OFF_W2B);
    const floatx4* PA  = (const floatx4*)(smem + OFF_PA);
    const floatx4* PB  = (const floatx4*)(smem + OFF_PB);
    const floatx2* ZA  = (const floatx2*)(smem + OFF_ZA);
    const floatx2* ZB  = (const floatx2*)(smem + OFF_ZB);
    const floatx4* B2RA = (const floatx4*)(smem + OFF_B2A);
    const floatx4* B2RB = (const floatx4*)(smem + OFF_B2B);
    const float*   W3A = (const float*)(smem + OFF_W3A);
    const floatx4* W3T = (const floatx4*)(smem + OFF_W3T);
    float*         SA  = (float*)(smem + OFF_SA);
    const float2* xA = (const float2*)x;
    const float2* xB = xA + BTOT;

    const float b3a_ = b3a[0];
    const float b30 = b3b[0], b31 = b3b[1], b32 = b3b[2];

    // ---- stage: x(a) loads + both paths' W2/W1/B2 + W3 ----
    float2 xv[4];   // [c*2+mt]
    #pragma unroll
    for (int c = 0; c < 2; ++c)
        #pragma unroll
        for (int mt = 0; mt < 2; ++mt)
            xv[c * 2 + mt] = xA[wbase + c * 32 + mt * 16 + col];

    pack_w2(smem + OFF_W2A, tid, w2a);
    pack_w2(smem + OFF_W2B, tid, w2b);
    if (tid < 64) {
        stage_w1(smem, OFF_PA, OFF_ZA, tid, w1a, b1a);
    } else if (tid < 128) {
        stage_w1(smem, OFF_PB, OFF_ZB, tid - 64, w1b, b1b);
    } else if (tid < 256) {
        int e = tid - 128; float b = b2a[e];
        ((floatx4*)(smem + OFF_B2A))[e] = (floatx4){b, b, b, b};
    } else if (tid < 384) {
        int e = tid - 256; float b = b2b[e];
        ((floatx4*)(smem + OFF_B2B))[e] = (floatx4){b, b, b, b};
    } else {
        int e = tid - 384;
        ((float*)(smem + OFF_W3A))[e] = w3a[e];
    }
    if (tid < 384) {                                  // transpose w3b [3][128]
        int j = tid >> 7, n = tid & 127;              //  -> [128][4]
        ((float*)(smem + OFF_W3T))[n * 4 + j] = w3b[tid];
    }
    __syncthreads();   // the ONLY barrier

    // ---- phase a ----
    #pragma unroll
    for (int c = 0; c < 2; ++c) {
        __builtin_amdgcn_sched_barrier(0);
        floatx4 acc[8][2];
        GEMM_CHUNK(acc, xv + 2 * c, PA, ZA, W2A, B2RA);
        __builtin_amdgcn_sched_barrier(0);

        float pa[2][4] = {};
        #pragma unroll
        for (int t = 0; t < 8; ++t) {
            float w3n = W3A[t * 16 + col];
            #pragma unroll
            for (int mt = 0; mt < 2; ++mt)
                #pragma unroll
                for (int r = 0; r < 4; ++r)
                    pa[mt][r] = fmaf(w3n, fmaxf(acc[t][mt][r], 0.f), pa[mt][r]);
        }
        #pragma unroll
        for (int mt = 0; mt < 2; ++mt) {
            float w = red4(pa[mt][0], pa[mt][1], pa[mt][2], pa[mt][3], col);
            if (col < 4) {
                int sl = mt * 16 + quad * 4 + col;
                SA[wave * 64 + c * 32 + sl] = (w + b3a_) * 1.44269504089f;
            }
        }
        __builtin_amdgcn_sched_barrier(0);
    }

    // ---- phase b: reload x, compute, softmax (no barriers needed) ----
    #pragma unroll
    for (int c = 0; c < 2; ++c)
        #pragma unroll
        for (int mt = 0; mt < 2; ++mt)
            xv[c * 2 + mt] = xB[wbase + c * 32 + mt * 16 + col];

    #pragma unroll
    for (int c = 0; c < 2; ++c) {
        __builtin_amdgcn_sched_barrier(0);
        floatx4 acc[8][2];
        GEMM_CHUNK(acc, xv + 2 * c, PB, ZB, W2B, B2RB);
        __builtin_amdgcn_sched_barrier(0);

        #pragma unroll
        for (int mt = 0; mt < 2; ++mt) {     // per-mt: 12 live partials
            float p0[4] = {}, p1[4] = {}, p2[4] = {};
            #pragma unroll
            for (int t = 0; t < 8; ++t) {
                floatx4 w3v = W3T[t * 16 + col];   // {w30,w31,w32,-}
                #pragma unroll
                for (int r = 0; r < 4; ++r) {
                    float h = fmaxf(acc[t][mt][r], 0.f);
                    p0[r] = fmaf(w3v.x, h, p0[r]);
                    p1[r] = fmaf(w3v.y, h, p1[r]);
                    p2[r] = fmaf(w3v.z, h, p2[r]);
                }
            }
            float t0 = red4(p0[0], p0[1], p0[2], p0[3], col) + b30;
            float t1 = red4(p1[0], p1[1], p1[2], p1[3], col) + b31;
            float t2 = red4(p2[0], p2[1], p2[2], p2[3], col) + b32;
            int sl = mt * 16 + quad * 4 + (col & 3);
            float sa = SA[wave * 64 + c * 32 + sl];   // log2-scaled s_a
            float y0 = sa * t0, y1 = sa * t1, y2 = sa * t2;
            float m = fmaxf(y0, fmaxf(y1, y2));
            float e0 = exp2f(y0 - m), e1 = exp2f(y1 - m), e2 = exp2f(y2 - m);
            float rs = __builtin_amdgcn_rcpf(e0 + e1 + e2);
            // cols 0..11: lane j*4+s stores component j of sample s
            float ev = (col >= 8) ? e2 : ((col >= 4) ? e1 : e0);
            if (col < 12) {
                long o = (long)(wbase + c * 32 + sl) * 3 + (col >> 2);
                out[o] = ev * rs;
            }
        }
        __builtin_amdgcn_sched_barrier(0);
    }
}

extern "C" void kernel_launch(void* const* d_in, const int* in_sizes, int n_in,
                              void* d_out, int out_size, void* d_ws, size_t ws_size,
                              hipStream_t stream) {
    const float* x   = (const float*)d_in[0];
    const float* w1a = (const float*)d_in[1];
    const float* w1b = (const float*)d_in[2];
    const float* b1a = (const float*)d_in[3];
    const float* b1b = (const float*)d_in[4];
    const float* w2a = (const float*)d_in[5];
    const float* w2b = (const float*)d_in[6];
    const float* b2a = (const float*)d_in[7];
    const float* b2b = (const float*)d_in[8];
    const float* w3a = (const float*)d_in[9];
    const float* w3b = (const float*)d_in[10];
    const float* b3a = (const float*)d_in[11];
    const float* b3b = (const float*)d_in[12];
    float* out = (float*)d_out;

    krone_fused<<<NBLK, 512, 0, stream>>>(x, w1a, w1b, b1a, b1b, w2a, w2b,
                                          b2a, b2b, w3a, w3b, b3a, b3b, out);
}

// Round 5
// 108.505 us; speedup vs baseline: 1.1135x; 1.1135x over previous
//
#include <hip/hip_runtime.h>
#include <hip/hip_bf16.h>

// ---------------------------------------------------------------------------
// KroneNet fused kernel v12 for MI355X (gfx950)  [resubmit: R4 bench was an
// infra failure -- container died twice, kernel never ran]
// out[i][j] = softmax_j( s_a[i] * t_j[i] )
// History: v8 40.9us / v9 ~36.5us / v10 FAILED (red4 mirror bug) /
// v11 50us REGRESSION: GEMM restructure (bias-as-MFMA-C + pk-FMA) spilled
// to scratch -- WRITE_SIZE 71.7MB vs 3.1MB output, FETCH +28MB, i.e.
// ~256B/thread spill traffic; VGPR_Count=64 is the launch_bounds cap, not
// proof of fit.
// v12: revert GEMM_CHUNK to v9's proven-fit form (scalar fmaf layer-1 from
// padded W1 float4 slots, b2-broadcast acc init). Keep the verified
// register-neutral wins from v10/v11:
//   - W2 double-buffered in LDS (75.7KB total, 2 blocks/CU), ONE
//     __syncthreads; no mid-kernel repack, no barriers after (SA within-wave)
//   - red4 multiplexed DPP butterfly (xor1/xor2 mux + row_ror:4/8 rotations;
//     rotation preserves c&3 so sample index never mixes -- v10 bug fixed,
//     verified passing in v11)
//   - softmax in log2 domain (SA pre-scaled by log2e), v_rcp divide,
//     spread store (cols 0-11 carry e0/e1/e2)
//   - all small buffers staged upfront
// ---------------------------------------------------------------------------

#define BTOT 262144
#define NBLK (BTOT / 512)   // 512 blocks x 512 samples (8 waves x 64)

typedef __attribute__((ext_vector_type(4))) float floatx4;
typedef __attribute__((ext_vector_type(8))) short bf16x8;
typedef __attribute__((ext_vector_type(4))) int  intx4;

// LDS layout (bytes)
#define OFF_W2A  0          // 32768
#define OFF_W2B  32768      // 32768
#define OFF_W1A  65536      // 144 float4 slots (padded)           = 2304
#define OFF_W1B  67840      // 2304
#define OFF_B2A  70144      // 128 * float                         = 512
#define OFF_B2B  70656      // 512
#define OFF_W3A  71168      // 128 * float                         = 512
#define OFF_W3T  71680      // 128 * float4 (w3b transposed [n][j])= 2048
#define OFF_SA   73728      // 512 * float (s_a * log2e)           = 2048
#define LDS_TOTAL 75776

// pack two fp32 -> one dword of two bf16, single VALU op (RNE)
static __device__ __forceinline__ int pack2bf(float lo, float hi) {
    int r;
    asm("v_cvt_pk_bf16_f32 %0, %1, %2" : "=v"(r) : "v"(lo), "v"(hi));
    return r;
}

// DPP-fused butterfly add: v += lanes-permuted(v), 1 VALU inst per stage.
// 0xB1=quad_perm xor1, 0x4E=quad_perm xor2,
// 0x124=row_ror:4, 0x128=row_ror:8 (true rotations within the 16-lane row)
template <int CTRL>
static __device__ __forceinline__ float dppadd(float v) {
    int t = __builtin_amdgcn_update_dpp(0, __builtin_bit_cast(int, v),
                                        CTRL, 0xF, 0xF, true);
    return v + __builtin_bit_cast(float, t);
}

// Multiplexed 4-value reduce over 16 cols: 12 insts; lane c ends with the
// 16-col sum of a_{c&3} (cols 0..3 hold a0..a3 directly).
// Stage 1: xor1-add each a_i, mux on bit0. Stage 2: xor2-add, mux on bit1.
// After stage 2 lane c holds the 4-group sum of a_{c&3} -- NOT low-bit
// uniform, so mirrors (xor7/xor15) are WRONG here (v10 bug). Stages 3,4:
// row_ror:4 + row_ror:8 -- the rotation transversal {c,c+4,c+8,c+12} sums
// all four group partials and (c+4k)&3 == c&3 keeps the a-index fixed.
static __device__ __forceinline__ float red4(float a0, float a1, float a2,
                                             float a3, int col) {
    float s0 = dppadd<0xB1>(a0), s1 = dppadd<0xB1>(a1);
    float s2 = dppadd<0xB1>(a2), s3 = dppadd<0xB1>(a3);
    float u0 = (col & 1) ? s1 : s0;
    float u1 = (col & 1) ? s3 : s2;
    float v0 = dppadd<0x4E>(u0), v1 = dppadd<0x4E>(u1);
    float w  = (col & 2) ? v1 : v0;
    w = dppadd<0x124>(w);   // += m[c+4]
    w = dppadd<0x128>(w);   // += m[c+8] + m[c+12]
    return w;
}

// W1 slot with bank-conflict padding: one extra float4 slot every 8 entries
static __device__ __forceinline__ int w1slot(int k) { return k + (k >> 3); }

// Pack one path's W2 into one LDS buffer (512 threads, 8 iters).
// W2 mapping (verified v5-v11): k=4*k4: dest = (s*8+t)*1024 + l*16 + (k&7)*2,
// s=k>>5, l=((k&31)>>3)*16+(n&15), t=n>>4. Lane remap keeps write
// conflicts <=4-way.
static __device__ __forceinline__ void pack_w2(
        unsigned char* dst, int tid, const float* __restrict__ w2) {
    const float4* w2p = (const float4*)w2;
    #pragma unroll
    for (int i = 0; i < 8; ++i) {
        int n  = (tid & 15) | (i << 4);
        int k4 = tid >> 4;
        float4 f = w2p[n * 32 + k4];
        int k = k4 * 4;
        int s = k >> 5;
        int j0 = k & 7;               // 0 or 4
        int l = ((k & 31) >> 3) * 16 + (n & 15);
        int2 pkd;
        pkd.x = pack2bf(f.x, f.y);
        pkd.y = pack2bf(f.z, f.w);
        *(int2*)(dst + (s * 8 + (n >> 4)) * 1024 + l * 16 + j0 * 2) = pkd;
    }
}

static __device__ __forceinline__ void stage_small(
        unsigned char* smem, int tid, int offW1, int offB2,
        const float* __restrict__ w1, const float* __restrict__ b1,
        const float* __restrict__ b2) {
    if (tid < 128) {
        ((float4*)(smem + offW1))[w1slot(tid)] =
            make_float4(w1[2 * tid], w1[2 * tid + 1], b1[tid], 0.f);
        ((float*)(smem + offB2))[tid] = b2[tid];
    }
}

// One chunk's GEMM: acc = W2 . relu(W1.x+b1) + b2 (acc pre-init with b2).
// acc layout: (t, mt, r) -> sample mt*16+quad*4+r, n = t*16+col.
// v9's proven-64-reg form: scalar fmaf layer-1, b2-broadcast init.
#define GEMM_CHUNK(acc, XV, W1p, W2p, B2p)                                     \
    {                                                                          \
        _Pragma("unroll")                                                      \
        for (int t = 0; t < 8; ++t) {                                          \
            float b2n = (B2p)[t * 16 + col];                                   \
            floatx4 bi = (floatx4){b2n, b2n, b2n, b2n};                        \
            _Pragma("unroll")                                                  \
            for (int mt = 0; mt < 2; ++mt) acc[t][mt] = bi;                    \
        }                                                                      \
        _Pragma("unroll")                                                      \
        for (int s = 0; s < 4; ++s) {                                          \
            intx4 af[2];                                                       \
            const int bslot = s * 36 + quad * 9;                               \
            _Pragma("unroll")                                                  \
            for (int j2 = 0; j2 < 4; ++j2) {                                   \
                float4 c0 = (W1p)[bslot + 2 * j2];                             \
                float4 c1 = (W1p)[bslot + 2 * j2 + 1];                         \
                _Pragma("unroll")                                              \
                for (int mt = 0; mt < 2; ++mt) {                               \
                    float h0 = fmaxf(fmaf((XV)[mt].x, c0.x,                    \
                                fmaf((XV)[mt].y, c0.y, c0.z)), 0.f);           \
                    float h1 = fmaxf(fmaf((XV)[mt].x, c1.x,                    \
                                fmaf((XV)[mt].y, c1.y, c1.z)), 0.f);           \
                    af[mt][j2] = pack2bf(h0, h1);                              \
                }                                                              \
            }                                                                  \
            _Pragma("unroll")                                                  \
            for (int t = 0; t < 8; ++t) {                                      \
                bf16x8 bfr = (W2p)[(s * 8 + t) * 64 + lane];                   \
                _Pragma("unroll")                                              \
                for (int mt = 0; mt < 2; ++mt)                                 \
                    acc[t][mt] = __builtin_amdgcn_mfma_f32_16x16x32_bf16(      \
                        __builtin_bit_cast(bf16x8, af[mt]), bfr,               \
                        acc[t][mt], 0, 0, 0);                                  \
            }                                                                  \
        }                                                                      \
    }

// ---------------------------------------------------------------------------
// 512 blocks x 512 threads (8 waves). Per block (512 samples):
//   stage EVERYTHING (both paths) -> one sync -> phase a (s_a->LDS) ->
//   phase b (t_j, softmax with LDS s_a, store) with no further barriers.
// ---------------------------------------------------------------------------
__global__ __launch_bounds__(512, 4)
void krone_fused(const float* __restrict__ x,
                 const float* __restrict__ w1a, const float* __restrict__ w1b,
                 const float* __restrict__ b1a, const float* __restrict__ b1b,
                 const float* __restrict__ w2a, const float* __restrict__ w2b,
                 const float* __restrict__ b2a, const float* __restrict__ b2b,
                 const float* __restrict__ w3a, const float* __restrict__ w3b,
                 const float* __restrict__ b3a, const float* __restrict__ b3b,
                 float* __restrict__ out) {
    __shared__ __align__(16) unsigned char smem[LDS_TOTAL];

    const int tid  = threadIdx.x;
    const int lane = tid & 63;
    const int wave = tid >> 6;
    const int quad = lane >> 4;
    const int col  = lane & 15;
    const int wbase = blockIdx.x * 512 + wave * 64;

    const bf16x8* W2A = (const bf16x8*)(smem + OFF_W2A);
    const bf16x8* W2B = (const bf16x8*)(smem + OFF_W2B);
    const float4* W1A = (const float4*)(smem + OFF_W1A);
    const float4* W1B = (const float4*)(smem + OFF_W1B);
    const float*  B2A = (const float*)(smem + OFF_B2A);
    const float*  B2B = (const float*)(smem + OFF_B2B);
    const float*  W3A = (const float*)(smem + OFF_W3A);
    const floatx4* W3T = (const floatx4*)(smem + OFF_W3T);
    float*        SA  = (float*)(smem + OFF_SA);
    const float2* xA = (const float2*)x;
    const float2* xB = xA + BTOT;

    const float b3a_ = b3a[0];
    const float b30 = b3b[0], b31 = b3b[1], b32 = b3b[2];

    // ---- stage: x(a) loads + both paths' W2/W1/B2 + W3 ----
    float2 xv[4];   // [c*2+mt]
    #pragma unroll
    for (int c = 0; c < 2; ++c)
        #pragma unroll
        for (int mt = 0; mt < 2; ++mt)
            xv[c * 2 + mt] = xA[wbase + c * 32 + mt * 16 + col];

    pack_w2(smem + OFF_W2A, tid, w2a);
    pack_w2(smem + OFF_W2B, tid, w2b);
    stage_small(smem, tid, OFF_W1A, OFF_B2A, w1a, b1a, b2a);
    stage_small(smem, tid, OFF_W1B, OFF_B2B, w1b, b1b, b2b);
    if (tid < 128) ((float*)(smem + OFF_W3A))[tid] = w3a[tid];
    if (tid < 384) {                                  // transpose w3b [3][128]
        int j = tid >> 7, n = tid & 127;              //  -> [128][4]
        ((float*)(smem + OFF_W3T))[n * 4 + j] = w3b[tid];
    }
    __syncthreads();   // the ONLY barrier

    // ---- phase a ----
    #pragma unroll
    for (int c = 0; c < 2; ++c) {
        __builtin_amdgcn_sched_barrier(0);
        floatx4 acc[8][2];
        GEMM_CHUNK(acc, xv + 2 * c, W1A, W2A, B2A);
        __builtin_amdgcn_sched_barrier(0);

        float pa[2][4] = {};
        #pragma unroll
        for (int t = 0; t < 8; ++t) {
            float w3n = W3A[t * 16 + col];
            #pragma unroll
            for (int mt = 0; mt < 2; ++mt)
                #pragma unroll
                for (int r = 0; r < 4; ++r)
                    pa[mt][r] = fmaf(w3n, fmaxf(acc[t][mt][r], 0.f), pa[mt][r]);
        }
        #pragma unroll
        for (int mt = 0; mt < 2; ++mt) {
            float w = red4(pa[mt][0], pa[mt][1], pa[mt][2], pa[mt][3], col);
            if (col < 4) {
                int sl = mt * 16 + quad * 4 + col;
                SA[wave * 64 + c * 32 + sl] = (w + b3a_) * 1.44269504089f;
            }
        }
        __builtin_amdgcn_sched_barrier(0);
    }

    // ---- phase b: reload x, compute, softmax (no barriers needed) ----
    #pragma unroll
    for (int c = 0; c < 2; ++c)
        #pragma unroll
        for (int mt = 0; mt < 2; ++mt)
            xv[c * 2 + mt] = xB[wbase + c * 32 + mt * 16 + col];

    #pragma unroll
    for (int c = 0; c < 2; ++c) {
        __builtin_amdgcn_sched_barrier(0);
        floatx4 acc[8][2];
        GEMM_CHUNK(acc, xv + 2 * c, W1B, W2B, B2B);
        __builtin_amdgcn_sched_barrier(0);

        #pragma unroll
        for (int mt = 0; mt < 2; ++mt) {     // per-mt: 12 live partials
            float p0[4] = {}, p1[4] = {}, p2[4] = {};
            #pragma unroll
            for (int t = 0; t < 8; ++t) {
                floatx4 w3v = W3T[t * 16 + col];   // {w30,w31,w32,-}
                #pragma unroll
                for (int r = 0; r < 4; ++r) {
                    float h = fmaxf(acc[t][mt][r], 0.f);
                    p0[r] = fmaf(w3v.x, h, p0[r]);
                    p1[r] = fmaf(w3v.y, h, p1[r]);
                    p2[r] = fmaf(w3v.z, h, p2[r]);
                }
            }
            float t0 = red4(p0[0], p0[1], p0[2], p0[3], col) + b30;
            float t1 = red4(p1[0], p1[1], p1[2], p1[3], col) + b31;
            float t2 = red4(p2[0], p2[1], p2[2], p2[3], col) + b32;
            int sl = mt * 16 + quad * 4 + (col & 3);
            float sa = SA[wave * 64 + c * 32 + sl];   // log2-scaled s_a
            float y0 = sa * t0, y1 = sa * t1, y2 = sa * t2;
            float m = fmaxf(y0, fmaxf(y1, y2));
            float e0 = exp2f(y0 - m), e1 = exp2f(y1 - m), e2 = exp2f(y2 - m);
            float rs = __builtin_amdgcn_rcpf(e0 + e1 + e2);
            // cols 0..11: lane j*4+s stores component j of sample s
            float ev = (col >= 8) ? e2 : ((col >= 4) ? e1 : e0);
            if (col < 12) {
                long o = (long)(wbase + c * 32 + sl) * 3 + (col >> 2);
                out[o] = ev * rs;
            }
        }
        __builtin_amdgcn_sched_barrier(0);
    }
}

extern "C" void kernel_launch(void* const* d_in, const int* in_sizes, int n_in,
                              void* d_out, int out_size, void* d_ws, size_t ws_size,
                              hipStream_t stream) {
    const float* x   = (const float*)d_in[0];
    const float* w1a = (const float*)d_in[1];
    const float* w1b = (const float*)d_in[2];
    const float* b1a = (const float*)d_in[3];
    const float* b1b = (const float*)d_in[4];
    const float* w2a = (const float*)d_in[5];
    const float* w2b = (const float*)d_in[6];
    const float* b2a = (const float*)d_in[7];
    const float* b2b = (const float*)d_in[8];
    const float* w3a = (const float*)d_in[9];
    const float* w3b = (const float*)d_in[10];
    const float* b3a = (const float*)d_in[11];
    const float* b3b = (const float*)d_in[12];
    float* out = (float*)d_out;

    krone_fused<<<NBLK, 512, 0, stream>>>(x, w1a, w1b, b1a, b1b, w2a, w2b,
                                          b2a, b2b, w3a, w3b, b3a, b3b, out);
}

// Round 6
// 105.386 us; speedup vs baseline: 1.1465x; 1.0296x over previous
//
#include <hip/hip_runtime.h>
#include <hip/hip_bf16.h>

// ---------------------------------------------------------------------------
// KroneNet fused kernel v13 for MI355X (gfx950)
// out[i][j] = softmax_j( s_a[i] * t_j[i] )
// History: v8 40.9us / v9 ~37-40us (cvt_pk, DPP red, W3T) / v10 FAILED
// (red4 mirror bug) / v11 50us (spill: bias-as-MFMA-C + pk-FMA) /
// v12 45.5us: spill fixed BUT the W2-double-buffer + all-upfront staging
// structure added ~6us of stall vs v9 (VALU-busy 18.0us, MfmaUtil-time
// 6.4us unchanged -- the regression is pure stall, not work).
// v13 = v9's measured-best structure + v12's verified instruction cuts:
//   - single 32KB W2 buffer, mid-kernel repack (xB loads hoisted above the
//     transition barriers to hide HBM latency) -- LDS back to 43KB
//   - red4 multiplexed DPP butterfly (xor1/xor2 mux + row_ror:4/8; rotation
//     preserves c&3 -- verified v11/v12)
//   - log2-domain softmax (SA pre-scaled by log2e), v_rcp divide
//   - compact 3-dword store (v12's spread store doubled WRITE_SIZE,
//     6.1MB vs 3.1MB output -- partial-line write amplification)
//   - pack2bf via v_cvt_pk_bf16_f32 asm; W3T transposed [n][4]
//   - GEMM_CHUNK is v9's proven-64-reg form (scalar fmaf layer-1,
//     b2-broadcast acc init) -- do NOT touch (v11 lesson)
// ---------------------------------------------------------------------------

#define BTOT 262144
#define NBLK (BTOT / 512)   // 512 blocks x 512 samples (8 waves x 64)

typedef __attribute__((ext_vector_type(4))) float floatx4;
typedef __attribute__((ext_vector_type(8))) short bf16x8;
typedef __attribute__((ext_vector_type(4))) int  intx4;

// LDS layout (bytes), one W2 path resident at a time
#define OFF_W2   0          // 4 ksteps * 8 ntiles * 64 lanes * 16B = 32768
#define OFF_W1A  32768      // 144 float4 slots (padded)           = 2304
#define OFF_W1B  35072      // 2304
#define OFF_B2A  37376      // 128 * float                         = 512
#define OFF_B2B  37888      // 512
#define OFF_W3A  38400      // 128 * float                         = 512
#define OFF_W3T  38912      // 128 * float4 (w3b transposed [n][j])= 2048
#define OFF_SA   40960      // 512 * float (s_a * log2e)           = 2048
#define LDS_TOTAL 43008

// pack two fp32 -> one dword of two bf16, single VALU op (RNE)
static __device__ __forceinline__ int pack2bf(float lo, float hi) {
    int r;
    asm("v_cvt_pk_bf16_f32 %0, %1, %2" : "=v"(r) : "v"(lo), "v"(hi));
    return r;
}

// DPP-fused butterfly add: v += lanes-permuted(v), 1 VALU inst per stage.
// 0xB1=quad_perm xor1, 0x4E=quad_perm xor2,
// 0x124=row_ror:4, 0x128=row_ror:8 (true rotations within the 16-lane row)
template <int CTRL>
static __device__ __forceinline__ float dppadd(float v) {
    int t = __builtin_amdgcn_update_dpp(0, __builtin_bit_cast(int, v),
                                        CTRL, 0xF, 0xF, true);
    return v + __builtin_bit_cast(float, t);
}

// Multiplexed 4-value reduce over 16 cols: 12 insts; lane c ends with the
// 16-col sum of a_{c&3} (cols 0..3 hold a0..a3 directly).
// Stage 1: xor1-add each a_i, mux on bit0. Stage 2: xor2-add, mux on bit1.
// After stage 2 lane c holds the 4-group sum of a_{c&3} -- NOT low-bit
// uniform, so mirrors (xor7/xor15) are WRONG here (v10 bug). Stages 3,4:
// row_ror:4 + row_ror:8 -- the rotation transversal {c,c+4,c+8,c+12} sums
// all four group partials and (c+4k)&3 == c&3 keeps the a-index fixed.
static __device__ __forceinline__ float red4(float a0, float a1, float a2,
                                             float a3, int col) {
    float s0 = dppadd<0xB1>(a0), s1 = dppadd<0xB1>(a1);
    float s2 = dppadd<0xB1>(a2), s3 = dppadd<0xB1>(a3);
    float u0 = (col & 1) ? s1 : s0;
    float u1 = (col & 1) ? s3 : s2;
    float v0 = dppadd<0x4E>(u0), v1 = dppadd<0x4E>(u1);
    float w  = (col & 2) ? v1 : v0;
    w = dppadd<0x124>(w);   // += m[c+4]
    w = dppadd<0x128>(w);   // += m[c+8] + m[c+12]
    return w;
}

// W1 slot with bank-conflict padding: one extra float4 slot every 8 entries
static __device__ __forceinline__ int w1slot(int k) { return k + (k >> 3); }

// Pack one path's W2 into LDS (512 threads, 8 iters).
// W2 mapping (verified v5-v12): k=4*k4: dest = (s*8+t)*1024 + l*16 + (k&7)*2,
// s=k>>5, l=((k&31)>>3)*16+(n&15), t=n>>4. Lane remap keeps write
// conflicts <=4-way.
static __device__ __forceinline__ void pack_w2(
        unsigned char* dst, int tid, const float* __restrict__ w2) {
    const float4* w2p = (const float4*)w2;
    #pragma unroll
    for (int i = 0; i < 8; ++i) {
        int n  = (tid & 15) | (i << 4);
        int k4 = tid >> 4;
        float4 f = w2p[n * 32 + k4];
        int k = k4 * 4;
        int s = k >> 5;
        int j0 = k & 7;               // 0 or 4
        int l = ((k & 31) >> 3) * 16 + (n & 15);
        int2 pkd;
        pkd.x = pack2bf(f.x, f.y);
        pkd.y = pack2bf(f.z, f.w);
        *(int2*)(dst + (s * 8 + (n >> 4)) * 1024 + l * 16 + j0 * 2) = pkd;
    }
}

static __device__ __forceinline__ void stage_small(
        unsigned char* smem, int tid, int offW1, int offB2,
        const float* __restrict__ w1, const float* __restrict__ b1,
        const float* __restrict__ b2) {
    if (tid < 128) {
        ((float4*)(smem + offW1))[w1slot(tid)] =
            make_float4(w1[2 * tid], w1[2 * tid + 1], b1[tid], 0.f);
        ((float*)(smem + offB2))[tid] = b2[tid];
    }
}

// One chunk's GEMM: acc = W2 . relu(W1.x+b1) + b2 (acc pre-init with b2).
// acc layout: (t, mt, r) -> sample mt*16+quad*4+r, n = t*16+col.
// v9's proven-64-reg form: scalar fmaf layer-1, b2-broadcast init.
#define GEMM_CHUNK(acc, XV, W1p, W2p, B2p)                                     \
    {                                                                          \
        _Pragma("unroll")                                                      \
        for (int t = 0; t < 8; ++t) {                                          \
            float b2n = (B2p)[t * 16 + col];                                   \
            floatx4 bi = (floatx4){b2n, b2n, b2n, b2n};                        \
            _Pragma("unroll")                                                  \
            for (int mt = 0; mt < 2; ++mt) acc[t][mt] = bi;                    \
        }                                                                      \
        _Pragma("unroll")                                                      \
        for (int s = 0; s < 4; ++s) {                                          \
            intx4 af[2];                                                       \
            const int bslot = s * 36 + quad * 9;                               \
            _Pragma("unroll")                                                  \
            for (int j2 = 0; j2 < 4; ++j2) {                                   \
                float4 c0 = (W1p)[bslot + 2 * j2];                             \
                float4 c1 = (W1p)[bslot + 2 * j2 + 1];                         \
                _Pragma("unroll")                                              \
                for (int mt = 0; mt < 2; ++mt) {                               \
                    float h0 = fmaxf(fmaf((XV)[mt].x, c0.x,                    \
                                fmaf((XV)[mt].y, c0.y, c0.z)), 0.f);           \
                    float h1 = fmaxf(fmaf((XV)[mt].x, c1.x,                    \
                                fmaf((XV)[mt].y, c1.y, c1.z)), 0.f);           \
                    af[mt][j2] = pack2bf(h0, h1);                              \
                }                                                              \
            }                                                                  \
            _Pragma("unroll")                                                  \
            for (int t = 0; t < 8; ++t) {                                      \
                bf16x8 bfr = (W2p)[(s * 8 + t) * 64 + lane];                   \
                _Pragma("unroll")                                              \
                for (int mt = 0; mt < 2; ++mt)                                 \
                    acc[t][mt] = __builtin_amdgcn_mfma_f32_16x16x32_bf16(      \
                        __builtin_bit_cast(bf16x8, af[mt]), bfr,               \
                        acc[t][mt], 0, 0, 0);                                  \
            }                                                                  \
        }                                                                      \
    }

// ---------------------------------------------------------------------------
// 512 blocks x 512 threads (8 waves). Per block (512 samples):
//   xa loads + small weights + pack W2a -> sync -> phase a (s_a -> LDS)
//   xb loads -> sync -> repack W2b -> sync -> phase b (t_j, softmax, store)
// ---------------------------------------------------------------------------
__global__ __launch_bounds__(512, 4)
void krone_fused(const float* __restrict__ x,
                 const float* __restrict__ w1a, const float* __restrict__ w1b,
                 const float* __restrict__ b1a, const float* __restrict__ b1b,
                 const float* __restrict__ w2a, const float* __restrict__ w2b,
                 const float* __restrict__ b2a, const float* __restrict__ b2b,
                 const float* __restrict__ w3a, const float* __restrict__ w3b,
                 const float* __restrict__ b3a, const float* __restrict__ b3b,
                 float* __restrict__ out) {
    __shared__ __align__(16) unsigned char smem[LDS_TOTAL];

    const int tid  = threadIdx.x;
    const int lane = tid & 63;
    const int wave = tid >> 6;
    const int quad = lane >> 4;
    const int col  = lane & 15;
    const int wbase = blockIdx.x * 512 + wave * 64;

    const bf16x8* W2  = (const bf16x8*)(smem + OFF_W2);
    const float4* W1A = (const float4*)(smem + OFF_W1A);
    const float4* W1B = (const float4*)(smem + OFF_W1B);
    const float*  B2A = (const float*)(smem + OFF_B2A);
    const float*  B2B = (const float*)(smem + OFF_B2B);
    const float*  W3A = (const float*)(smem + OFF_W3A);
    const floatx4* W3T = (const floatx4*)(smem + OFF_W3T);
    float*        SA  = (float*)(smem + OFF_SA);
    const float2* xA = (const float2*)x;
    const float2* xB = xA + BTOT;

    const float b3a_ = b3a[0];
    const float b30 = b3b[0], b31 = b3b[1], b32 = b3b[2];

    // ---- stage: x(a) loads + all small weights + W2a pack ----
    float2 xv[4];   // [c*2+mt]
    #pragma unroll
    for (int c = 0; c < 2; ++c)
        #pragma unroll
        for (int mt = 0; mt < 2; ++mt)
            xv[c * 2 + mt] = xA[wbase + c * 32 + mt * 16 + col];

    pack_w2(smem + OFF_W2, tid, w2a);
    stage_small(smem, tid, OFF_W1A, OFF_B2A, w1a, b1a, b2a);
    stage_small(smem, tid, OFF_W1B, OFF_B2B, w1b, b1b, b2b);
    if (tid < 128) ((float*)(smem + OFF_W3A))[tid] = w3a[tid];
    if (tid < 384) {                                  // transpose w3b [3][128]
        int j = tid >> 7, n = tid & 127;              //  -> [128][4]
        ((float*)(smem + OFF_W3T))[n * 4 + j] = w3b[tid];
    }
    __syncthreads();

    // ---- phase a ----
    #pragma unroll
    for (int c = 0; c < 2; ++c) {
        __builtin_amdgcn_sched_barrier(0);
        floatx4 acc[8][2];
        GEMM_CHUNK(acc, xv + 2 * c, W1A, W2, B2A);
        __builtin_amdgcn_sched_barrier(0);

        float pa[2][4] = {};
        #pragma unroll
        for (int t = 0; t < 8; ++t) {
            float w3n = W3A[t * 16 + col];
            #pragma unroll
            for (int mt = 0; mt < 2; ++mt)
                #pragma unroll
                for (int r = 0; r < 4; ++r)
                    pa[mt][r] = fmaf(w3n, fmaxf(acc[t][mt][r], 0.f), pa[mt][r]);
        }
        #pragma unroll
        for (int mt = 0; mt < 2; ++mt) {
            float w = red4(pa[mt][0], pa[mt][1], pa[mt][2], pa[mt][3], col);
            if (col < 4) {
                int sl = mt * 16 + quad * 4 + col;
                SA[wave * 64 + c * 32 + sl] = (w + b3a_) * 1.44269504089f;
            }
        }
        __builtin_amdgcn_sched_barrier(0);
    }

    // ---- phase b transition: xB loads first (hide HBM latency under
    //      the barrier + W2 repack), then repack ----
    #pragma unroll
    for (int c = 0; c < 2; ++c)
        #pragma unroll
        for (int mt = 0; mt < 2; ++mt)
            xv[c * 2 + mt] = xB[wbase + c * 32 + mt * 16 + col];

    __syncthreads();   // everyone done reading W2a
    pack_w2(smem + OFF_W2, tid, w2b);
    __syncthreads();

    // ---- phase b ----
    #pragma unroll
    for (int c = 0; c < 2; ++c) {
        __builtin_amdgcn_sched_barrier(0);
        floatx4 acc[8][2];
        GEMM_CHUNK(acc, xv + 2 * c, W1B, W2, B2B);
        __builtin_amdgcn_sched_barrier(0);

        #pragma unroll
        for (int mt = 0; mt < 2; ++mt) {     // per-mt: 12 live partials
            float p0[4] = {}, p1[4] = {}, p2[4] = {};
            #pragma unroll
            for (int t = 0; t < 8; ++t) {
                floatx4 w3v = W3T[t * 16 + col];   // {w30,w31,w32,-}
                #pragma unroll
                for (int r = 0; r < 4; ++r) {
                    float h = fmaxf(acc[t][mt][r], 0.f);
                    p0[r] = fmaf(w3v.x, h, p0[r]);
                    p1[r] = fmaf(w3v.y, h, p1[r]);
                    p2[r] = fmaf(w3v.z, h, p2[r]);
                }
            }
            float t0 = red4(p0[0], p0[1], p0[2], p0[3], col) + b30;
            float t1 = red4(p1[0], p1[1], p1[2], p1[3], col) + b31;
            float t2 = red4(p2[0], p2[1], p2[2], p2[3], col) + b32;
            if (col < 4) {
                int sl = mt * 16 + quad * 4 + col;   // red4: lane col holds
                float sa = SA[wave * 64 + c * 32 + sl];  // sample col&3 ✓
                float y0 = sa * t0, y1 = sa * t1, y2 = sa * t2;
                float m = fmaxf(y0, fmaxf(y1, y2));
                float e0 = exp2f(y0 - m), e1 = exp2f(y1 - m), e2 = exp2f(y2 - m);
                float rs = __builtin_amdgcn_rcpf(e0 + e1 + e2);
                long o = (long)(wbase + c * 32 + sl) * 3;
                out[o]     = e0 * rs;
                out[o + 1] = e1 * rs;
                out[o + 2] = e2 * rs;
            }
        }
        __builtin_amdgcn_sched_barrier(0);
    }
}

extern "C" void kernel_launch(void* const* d_in, const int* in_sizes, int n_in,
                              void* d_out, int out_size, void* d_ws, size_t ws_size,
                              hipStream_t stream) {
    const float* x   = (const float*)d_in[0];
    const float* w1a = (const float*)d_in[1];
    const float* w1b = (const float*)d_in[2];
    const float* b1a = (const float*)d_in[3];
    const float* b1b = (const float*)d_in[4];
    const float* w2a = (const float*)d_in[5];
    const float* w2b = (const float*)d_in[6];
    const float* b2a = (const float*)d_in[7];
    const float* b2b = (const float*)d_in[8];
    const float* w3a = (const float*)d_in[9];
    const float* w3b = (const float*)d_in[10];
    const float* b3a = (const float*)d_in[11];
    const float* b3b = (const float*)d_in[12];
    float* out = (float*)d_out;

    krone_fused<<<NBLK, 512, 0, stream>>>(x, w1a, w1b, b1a, b1b, w2a, w2b,
                                          b2a, b2b, w3a, w3b, b3a, b3b, out);
}